// Round 9
// baseline (507.022 us; speedup 1.0000x reference)
//
#include <hip/hip_runtime.h>

typedef __bf16 bf16_t;
typedef bf16_t v8bf __attribute__((ext_vector_type(8)));
typedef bf16_t v4bf __attribute__((ext_vector_type(4)));
typedef float v16f __attribute__((ext_vector_type(16)));

#define NV 1024
#define ND 256
#define NR 65536
#define BM 32
#define KC 256          // logit cols per chunk
#define CT 16           // kt steps per chunk (KC/16)
#define NCH 4           // chunks per row (NV/KC)

// codebook fp32 [V][D] -> cws bf16 [kt=64][d=256][ki=16]  (k = kt*16+ki)
// coalesced float4 reads, scattered 2B writes (posted)
__global__ void prep_codebook(const float* __restrict__ cb, bf16_t* __restrict__ cws) {
    int g  = blockIdx.x * blockDim.x + threadIdx.x;   // 0..65535
    int v  = g >> 6;                                  // codebook row = k
    int d0 = (g & 63) * 4;
    const float4 x = *(const float4*)(cb + v * ND + d0);
    bf16_t* base = cws + (v >> 4) * 4096 + (v & 15);  // [kt][*][ki]
    base[(d0 + 0) * 16] = (bf16_t)x.x;
    base[(d0 + 1) * 16] = (bf16_t)x.y;
    base[(d0 + 2) * 16] = (bf16_t)x.z;
    base[(d0 + 3) * 16] = (bf16_t)x.w;
}

__device__ inline v4bf exp4(float4 x, float& s) {
    v4bf e;
    e[0] = (bf16_t)__expf(x.x);
    e[1] = (bf16_t)__expf(x.y);
    e[2] = (bf16_t)__expf(x.z);
    e[3] = (bf16_t)__expf(x.w);
    // sum the bf16-rounded values so normalization matches the matmul operand
    s += (float)e[0] + (float)e[1] + (float)e[2] + (float)e[3];
    return e;
}

__global__ __launch_bounds__(256, 4)
void scl_main(const float* __restrict__ logits,
              const int* __restrict__ targets,
              const float* __restrict__ cbf,     // fp32 codebook [V][D]
              const bf16_t* __restrict__ cws,    // bf16 tiled codebook
              float* __restrict__ out) {
    // double-buffered exp chunks: [2][32 rows][256 cols] bf16, row stride 512B,
    // XOR-swizzled byte ^= ((row&7)<<4)
    __shared__ char  sE[2][BM * 512];
    __shared__ float sSum[BM];

    const int tid  = (int)threadIdx.x;
    const int w    = tid >> 6;        // wave 0..3
    const int l    = tid & 63;        // lane
    const int brow = (int)blockIdx.x * BM;

    float srow[8] = {0, 0, 0, 0, 0, 0, 0, 0};

    // MFMA operand setup (wave w covers all 32 rows x cols [w*64, w*64+64))
    const int rA  = l & 31;
    const int g8  = l >> 5;
    const int swA = (rA & 7) << 4;
    const int cb0 = w << 6;
    const bf16_t* bBase = cws + (size_t)(cb0 + (l & 31)) * 16 + g8 * 8;

    v16f acc0 = {0,0,0,0,0,0,0,0,0,0,0,0,0,0,0,0};
    v16f acc1 = {0,0,0,0,0,0,0,0,0,0,0,0,0,0,0,0};

    for (int c = 0; c < NCH; ++c) {
        char* buf = sE[c & 1];
        // load chunk c (short live ranges -> no spill), exp -> swizzled LDS
#pragma unroll
        for (int rr = 0; rr < 8; ++rr) {
            const int r = w * 8 + rr;
            float4 x = ((const float4*)(logits +
                        (size_t)(brow + r) * NV + c * KC))[l];
            v4bf e = exp4(x, srow[rr]);
            *(v4bf*)(buf + r * 512 + ((l * 8) ^ ((r & 7) << 4))) = e;
        }
        // one barrier per chunk: WAR on sE[c&1] (re-written at c+2) is ordered
        // by this barrier at c+1; MFMA(c) reads complete before each wave's
        // write(c+2) because write(c+2) follows barrier(c+1).
        __syncthreads();
        const char* aBase = buf + rA * 512;
#pragma unroll 4
        for (int ktl = 0; ktl < CT; ++ktl) {
            const int kt   = c * CT + ktl;
            const int koff = ((ktl << 5) | (g8 << 4)) ^ swA;
            v8bf a  = *(const v8bf*)(aBase + koff);
            v8bf b0 = *(const v8bf*)(bBase + (size_t)kt * 4096);
            v8bf b1 = *(const v8bf*)(bBase + (size_t)kt * 4096 + 512);
            acc0 = __builtin_amdgcn_mfma_f32_32x32x16_bf16(a, b0, acc0, 0, 0, 0);
            acc1 = __builtin_amdgcn_mfma_f32_32x32x16_bf16(a, b1, acc1, 0, 0, 0);
        }
    }

    // row sums -> LDS
#pragma unroll
    for (int rr = 0; rr < 8; ++rr) {
        float s = srow[rr];
#pragma unroll
        for (int off = 32; off > 0; off >>= 1)
            s += __shfl_xor(s, off, 64);
        if (l == 0) sSum[w * 8 + rr] = s;
    }
    __syncthreads();

    // ---------------- Epilogue ----------------
    // C/D layout (verified): col = lane&31, row = (reg&3) + 8*(reg>>2) + 4*(lane>>5)
    float local = 0.f;
    const int c0  = cb0 + (l & 31);
    const int rb4 = (l >> 5) << 2;
#pragma unroll
    for (int q = 0; q < 16; ++q) {
        const int rloc = (q & 3) + ((q >> 2) << 3) + rb4;
        const int grow = brow + rloc;
        const float rs = __builtin_amdgcn_rcpf(sSum[rloc]);
        const int tgt  = targets[grow];
        const float* cr = cbf + (size_t)tgt * ND;
        float d0 = acc0[q] * rs - cr[c0];
        float d1 = acc1[q] * rs - cr[c0 + 32];
        local = fmaf(d0, d0, fmaf(d1, d1, local));
    }
#pragma unroll
    for (int off = 32; off > 0; off >>= 1)
        local += __shfl_xor(local, off, 64);
    if (l == 0)
        atomicAdd(out, local * (1.0f / (65536.0f * 256.0f)));
}

extern "C" void kernel_launch(void* const* d_in, const int* in_sizes, int n_in,
                              void* d_out, int out_size, void* d_ws, size_t ws_size,
                              hipStream_t stream) {
    const float* logits  = (const float*)d_in[0];
    const int*   targets = (const int*)d_in[1];
    const float* cbf     = (const float*)d_in[2];

    bf16_t* cws = (bf16_t*)d_ws;                        // 512 KB scratch
    float*  out = (float*)d_out;

    hipMemsetAsync(d_out, 0, sizeof(float), stream);
    prep_codebook<<<256, 256, 0, stream>>>(cbf, cws);
    scl_main<<<2048, 256, 0, stream>>>(logits, targets, cbf, cws, out);
}

// Round 10
// 467.861 us; speedup vs baseline: 1.0837x; 1.0837x over previous
//
#include <hip/hip_runtime.h>

typedef __bf16 bf16_t;
typedef bf16_t v8bf __attribute__((ext_vector_type(8)));
typedef bf16_t v4bf __attribute__((ext_vector_type(4)));
typedef float v16f __attribute__((ext_vector_type(16)));

#define NV 1024
#define ND 256
#define NR 65536
#define BM 32
#define KC 256          // logit cols per chunk
#define CT 16           // kt steps per chunk (KC/16)
#define NCH 4           // chunks per row (NV/KC)

// codebook fp32 [V][D] -> cws bf16 [kt=64][d=256][ki=16]  (k = kt*16+ki)
// coalesced float4 reads, scattered 2B writes (posted)
__global__ void prep_codebook(const float* __restrict__ cb, bf16_t* __restrict__ cws) {
    int g  = blockIdx.x * blockDim.x + threadIdx.x;   // 0..65535
    int v  = g >> 6;                                  // codebook row = k
    int d0 = (g & 63) * 4;
    const float4 x = *(const float4*)(cb + v * ND + d0);
    bf16_t* base = cws + (v >> 4) * 4096 + (v & 15);  // [kt][*][ki]
    base[(d0 + 0) * 16] = (bf16_t)x.x;
    base[(d0 + 1) * 16] = (bf16_t)x.y;
    base[(d0 + 2) * 16] = (bf16_t)x.z;
    base[(d0 + 3) * 16] = (bf16_t)x.w;
}

__device__ inline v4bf exp4(float4 x, float& s) {
    v4bf e;
    e[0] = (bf16_t)__expf(x.x);
    e[1] = (bf16_t)__expf(x.y);
    e[2] = (bf16_t)__expf(x.z);
    e[3] = (bf16_t)__expf(x.w);
    // sum the bf16-rounded values so normalization matches the matmul operand
    s += (float)e[0] + (float)e[1] + (float)e[2] + (float)e[3];
    return e;
}

// launch_bounds(256,2): the ,4 variant forces the allocator to the 64-VGPR
// step and spills ~115 MB of scratch (measured r5/r9). (256,2) → 88 VGPR,
// no spill (r3); occupancy is then LDS-limited at 4 blocks/CU (32.5 KB LDS).
__global__ __launch_bounds__(256, 2)
void scl_main(const float* __restrict__ logits,
              const int* __restrict__ targets,
              const float* __restrict__ cbf,     // fp32 codebook [V][D]
              const bf16_t* __restrict__ cws,    // bf16 tiled codebook
              float* __restrict__ out) {
    // double-buffered exp chunks: [2][32 rows][256 cols] bf16, row stride 512B,
    // XOR-swizzled byte ^= ((row&7)<<4)
    __shared__ char  sE[2][BM * 512];
    __shared__ float sSum[BM];

    const int tid  = (int)threadIdx.x;
    const int w    = tid >> 6;        // wave 0..3
    const int l    = tid & 63;        // lane
    const int brow = (int)blockIdx.x * BM;

    float srow[8] = {0, 0, 0, 0, 0, 0, 0, 0};

    // MFMA operand setup (wave w covers all 32 rows x cols [w*64, w*64+64))
    const int rA  = l & 31;
    const int g8  = l >> 5;
    const int swA = (rA & 7) << 4;
    const int cb0 = w << 6;
    const bf16_t* bBase = cws + (size_t)(cb0 + (l & 31)) * 16 + g8 * 8;

    v16f acc0 = {0,0,0,0,0,0,0,0,0,0,0,0,0,0,0,0};
    v16f acc1 = {0,0,0,0,0,0,0,0,0,0,0,0,0,0,0,0};

    for (int c = 0; c < NCH; ++c) {
        char* buf = sE[c & 1];
        // load chunk c (short live ranges -> no spill), exp -> swizzled LDS
#pragma unroll
        for (int rr = 0; rr < 8; ++rr) {
            const int r = w * 8 + rr;
            float4 x = ((const float4*)(logits +
                        (size_t)(brow + r) * NV + c * KC))[l];
            v4bf e = exp4(x, srow[rr]);
            *(v4bf*)(buf + r * 512 + ((l * 8) ^ ((r & 7) << 4))) = e;
        }
        // one barrier per chunk: WAR on sE[c&1] (re-written at c+2) is ordered
        // by this barrier at c+1; MFMA(c) reads complete before each wave's
        // write(c+2) because write(c+2) follows barrier(c+1).
        __syncthreads();
        const char* aBase = buf + rA * 512;
#pragma unroll 4
        for (int ktl = 0; ktl < CT; ++ktl) {
            const int kt   = c * CT + ktl;
            const int koff = ((ktl << 5) | (g8 << 4)) ^ swA;
            v8bf a  = *(const v8bf*)(aBase + koff);
            v8bf b0 = *(const v8bf*)(bBase + (size_t)kt * 4096);
            v8bf b1 = *(const v8bf*)(bBase + (size_t)kt * 4096 + 512);
            acc0 = __builtin_amdgcn_mfma_f32_32x32x16_bf16(a, b0, acc0, 0, 0, 0);
            acc1 = __builtin_amdgcn_mfma_f32_32x32x16_bf16(a, b1, acc1, 0, 0, 0);
        }
    }

    // row sums -> LDS
#pragma unroll
    for (int rr = 0; rr < 8; ++rr) {
        float s = srow[rr];
#pragma unroll
        for (int off = 32; off > 0; off >>= 1)
            s += __shfl_xor(s, off, 64);
        if (l == 0) sSum[w * 8 + rr] = s;
    }
    __syncthreads();

    // ---------------- Epilogue ----------------
    // C/D layout (verified): col = lane&31, row = (reg&3) + 8*(reg>>2) + 4*(lane>>5)
    float local = 0.f;
    const int c0  = cb0 + (l & 31);
    const int rb4 = (l >> 5) << 2;
#pragma unroll
    for (int q = 0; q < 16; ++q) {
        const int rloc = (q & 3) + ((q >> 2) << 3) + rb4;
        const int grow = brow + rloc;
        const float rs = __builtin_amdgcn_rcpf(sSum[rloc]);
        const int tgt  = targets[grow];
        const float* cr = cbf + (size_t)tgt * ND;
        float d0 = acc0[q] * rs - cr[c0];
        float d1 = acc1[q] * rs - cr[c0 + 32];
        local = fmaf(d0, d0, fmaf(d1, d1, local));
    }
#pragma unroll
    for (int off = 32; off > 0; off >>= 1)
        local += __shfl_xor(local, off, 64);
    if (l == 0)
        atomicAdd(out, local * (1.0f / (65536.0f * 256.0f)));
}

extern "C" void kernel_launch(void* const* d_in, const int* in_sizes, int n_in,
                              void* d_out, int out_size, void* d_ws, size_t ws_size,
                              hipStream_t stream) {
    const float* logits  = (const float*)d_in[0];
    const int*   targets = (const int*)d_in[1];
    const float* cbf     = (const float*)d_in[2];

    bf16_t* cws = (bf16_t*)d_ws;                        // 512 KB scratch
    float*  out = (float*)d_out;

    hipMemsetAsync(d_out, 0, sizeof(float), stream);
    prep_codebook<<<256, 256, 0, stream>>>(cbf, cws);
    scl_main<<<2048, 256, 0, stream>>>(logits, targets, cbf, cws, out);
}